// Round 15
// baseline (58.075 us; speedup 1.0000x reference)
//
#include <hip/hip_runtime.h>
#include <hip/hip_bf16.h>
#include <hip/hip_fp8.h>

#define N_TOT 8192
#define DIM 256                              // k elements = bytes (fp8)
#define HALF_B 4096
#define NCHUNK 32                            // 256-row chunks
#define NPAIR (NCHUNK * (NCHUNK + 1) / 2)    // 528 upper-tri pairs
#define NBLK (NPAIR * 4)                     // 2112 quarter-blocks (g,h)
#define TILE_COLS 32
#define NTILES 4                             // 4 x 32 = 128 cols per block
#define NSLOT 128                            // per-row: [2s]=rowsum slot s, [2s+1]=colsum slot s
#define LSE_BLOCKS (N_TOT / 4)               // 2048
#define KEXP 2.8853900817779268f             // (1/T=2) * log2(e)
#define TILE_BYTES (TILE_COLS * DIM)         // 8192 B per staged tile

typedef __attribute__((ext_vector_type(4))) float facc;      // 4 f32 accum
typedef __attribute__((ext_vector_type(2))) long long lpair; // 16B = 2 fp8 ksteps

typedef __attribute__((address_space(1))) const unsigned int guint;
typedef __attribute__((address_space(3))) unsigned int luint;

static __device__ __forceinline__ void gload16(const void* g, void* l) {
    __builtin_amdgcn_global_load_lds((guint*)g, (luint*)l, 16, 0, 0);
}
static __device__ __forceinline__ unsigned char f2fp8(float x) {
    __hip_fp8_e4m3 h(x);
    return (unsigned char)h.__x;
}
static __device__ __forceinline__ float fast_exp2(float x) {
#if __has_builtin(__builtin_amdgcn_exp2f)
    return __builtin_amdgcn_exp2f(x);
#else
    return exp2f(x);
#endif
}
static __device__ __forceinline__ facc mfma8(long long a, long long b, facc c) {
    return __builtin_amdgcn_mfma_f32_16x16x32_fp8_fp8(a, b, c, 0, 0, 0);
}

// Kernel 1: row-normalize concat(z_i, z_j) -> fp8 znP, kq-major permuted rows
__global__ __launch_bounds__(256) void norm_kernel(const float* __restrict__ zi,
                                                   const float* __restrict__ zj,
                                                   unsigned char* __restrict__ znP) {
    int row  = blockIdx.x * 4 + (threadIdx.x >> 6);
    int lane = threadIdx.x & 63;
    const float* src = (row < HALF_B) ? (zi + (size_t)row * DIM)
                                      : (zj + (size_t)(row - HALF_B) * DIM);
    float4 v = reinterpret_cast<const float4*>(src)[lane];
    float ss = v.x * v.x + v.y * v.y + v.z * v.z + v.w * v.w;
    #pragma unroll
    for (int off = 32; off; off >>= 1) ss += __shfl_xor(ss, off);
    float inv = 1.0f / fmaxf(sqrtf(ss), 1e-8f);
    uchar4 o;
    o.x = f2fp8(v.x * inv);
    o.y = f2fp8(v.y * inv);
    o.z = f2fp8(v.z * inv);
    o.w = f2fp8(v.w * inv);
    int b = lane * 4;                 // natural byte offset
    int g = b >> 3;                   // granule: natural g = ks*4+kq
    int pb = ((((g & 3) << 3) | (g >> 2)) << 3) | (b & 7);   // permuted = kq*8+ks
    *reinterpret_cast<uchar4*>(znP + (size_t)row * DIM + pb) = o;
}

// Kernel 2: symmetric fused zn@zn^T (fp8 MFMA) + exp sums + pos extraction.
// Block = quarter (i,j,g,h): rows = chunk i half g (128), cols = chunk j half h (128).
// 2 waves x 64 rows/wave: each B lpair read feeds 8 MFMAs (2x the LDS reuse
// of the 4x32 variant). Pinned A = a[4][4] lpairs = 64 VGPR (fp8).
// rowsum -> partial[row][2*(2j+h)]; colsum (i<j) -> partial[col][2*(2i+g)+1];
// pos tile (j==i+16, g==h): sim[r][r+4096]*2 -> pos[r], pos[r+4096].
__global__ __launch_bounds__(128, 4) void sim_kernel(const unsigned char* __restrict__ znP,
                                                     float* __restrict__ partial,
                                                     float* __restrict__ pos) {
    __shared__ __align__(16) unsigned char smem[2 * TILE_BYTES];   // 16KB dbuf
    __shared__ float colred[2][128];                               // 1KB
    const int lane = threadIdx.x & 63;
    const int wv   = threadIdx.x >> 6;          // 0..1
    const int lrow = lane & 15;         // A-row / B-col within 16
    const int kq   = lane >> 4;         // k-group 0..3

    // decode block -> (i, j, g, h)
    const int pairId = blockIdx.x >> 2;
    const int h      = blockIdx.x & 1;
    const int g      = (blockIdx.x >> 1) & 1;
    int i = 0, rem = pairId;
    while (rem >= NCHUNK - i) { rem -= NCHUNK - i; ++i; }
    const int j = i + rem;
    const int rowBase  = i * 256 + g * 128 + wv * 64;
    const int colStart = j * 256 + h * 128;

    // staging: tile = 32 rows x 16 chunks(16B) = 512 chunks; 4 per thread
    int srcOff[4];
    #pragma unroll
    for (int q = 0; q < 4; ++q) {
        int c  = (wv * 4 + q) * 64 + lane;   // chunk id 0..511
        int r  = c >> 4;                     // tile row 0..31
        int cc = c & 15;                     // chunk-in-row (k-pair slot)
        srcOff[q] = r * DIM + ((cc ^ (r & 15)) << 4);   // pre-swizzled source
    }
    const unsigned char* znPC = znP + (size_t)colStart * DIM;

#define STAGE(buf, ct) do {                                                   \
        const unsigned char* gsb = znPC + (size_t)(ct) * TILE_BYTES;          \
        _Pragma("unroll")                                                     \
        for (int q = 0; q < 4; ++q)                                           \
            gload16(gsb + srcOff[q],                                          \
                    smem + (buf) * TILE_BYTES + (wv * 4 + q) * 1024);         \
    } while (0)

    STAGE(0, 0);

    // A fragments: 4 row-tiles x 4 k-pairs (16B each) = 64 VGPRs, resident.
    lpair a[4][4];
    #pragma unroll
    for (int t = 0; t < 4; ++t)
        #pragma unroll
        for (int s = 0; s < 4; ++s)
            a[t][s] = *reinterpret_cast<const lpair*>(
                znP + (size_t)(rowBase + t * 16 + lrow) * DIM + kq * 64 + s * 16);
    #pragma unroll
    for (int t = 0; t < 4; ++t)
        #pragma unroll
        for (int s = 0; s < 4; ++s)
            asm volatile("" : "+v"(a[t][s]));

    float rowsum[4][4];
    #pragma unroll
    for (int t = 0; t < 4; ++t)
        #pragma unroll
        for (int jj = 0; jj < 4; ++jj) rowsum[t][jj] = 0.0f;

    colred[wv][lane]      = 0.0f;
    colred[wv][lane + 64] = 0.0f;

    __syncthreads();            // tile 0 staged; colred zeroed

    #pragma unroll 1
    for (int tile = 0; tile < NTILES; ++tile) {
        const int cur = tile & 1;
        if (tile + 1 < NTILES) STAGE(cur ^ 1, tile + 1);   // hides under MFMA

        #pragma unroll
        for (int cs = 0; cs < 2; ++cs) {                   // 16-col subtiles
            const unsigned char* base =
                smem + cur * TILE_BYTES + (cs * 16 + lrow) * DIM;
            facc acc[4];
            #pragma unroll
            for (int t = 0; t < 4; ++t) acc[t] = (facc){0.f, 0.f, 0.f, 0.f};
            #pragma unroll
            for (int s = 0; s < 4; ++s) {                  // k-pair (2 ksteps)
                lpair bv = *reinterpret_cast<const lpair*>(
                    base + (((kq * 4 + s) ^ lrow) << 4));
                #pragma unroll
                for (int t = 0; t < 4; ++t) {
                    acc[t] = mfma8(a[t][s][0], bv[0], acc[t]);
                    acc[t] = mfma8(a[t][s][1], bv[1], acc[t]);
                }
            }

            const int colBase = colStart + tile * TILE_COLS + cs * 16;
            float csum = 0.0f;
            #pragma unroll
            for (int t = 0; t < 4; ++t) {
                const int tRowBase = rowBase + t * 16;
                if (colBase == tRowBase) {                 // self-diagonal tile
                    #pragma unroll
                    for (int jj = 0; jj < 4; ++jj) {
                        float e = fast_exp2(acc[t][jj] * KEXP);
                        if (lrow == kq * 4 + jj) e = 0.0f; // exclude self
                        rowsum[t][jj] += e;
                        csum += e;
                    }
                } else if (colBase == tRowBase + HALF_B) { // positive-pair tile
                    #pragma unroll
                    for (int jj = 0; jj < 4; ++jj) {
                        float e = fast_exp2(acc[t][jj] * KEXP);
                        rowsum[t][jj] += e;
                        csum += e;
                        if (lrow == kq * 4 + jj) {         // sim[r][r+B]
                            int r = tRowBase + lrow;
                            float p = acc[t][jj] * 2.0f;
                            pos[r]          = p;
                            pos[r + HALF_B] = p;           // symmetric twin
                        }
                    }
                } else {
                    #pragma unroll
                    for (int jj = 0; jj < 4; ++jj) {
                        float e = fast_exp2(acc[t][jj] * KEXP);
                        rowsum[t][jj] += e;
                        csum += e;
                    }
                }
            }
            // col-sum: reduce across kq groups, accumulate into LDS
            csum += __shfl_xor(csum, 16);
            csum += __shfl_xor(csum, 32);
            if (kq == 0)
                colred[wv][tile * TILE_COLS + cs * 16 + lrow] += csum;
        }
        __syncthreads();   // next tile staged; reads of buf[cur] done
    }
#undef STAGE

    // rowsum: reduce across 16 lrow lanes -> partial[row][2*(2j+h)]
    const int offR = (j * 2 + h) * 2;
    #pragma unroll
    for (int t = 0; t < 4; ++t)
        #pragma unroll
        for (int jj = 0; jj < 4; ++jj) {
            float v = rowsum[t][jj];
            v += __shfl_xor(v, 1);
            v += __shfl_xor(v, 2);
            v += __shfl_xor(v, 4);
            v += __shfl_xor(v, 8);
            if (lrow == 0)
                partial[(size_t)(rowBase + t * 16 + kq * 4 + jj) * NSLOT + offR] = v;
        }

    // colsum: cross-wave reduce -> partial[col][2*(2i+g)+1]
    if (i != j) {
        int c = threadIdx.x;
        float s = colred[0][c] + colred[1][c];
        partial[(size_t)(colStart + c) * NSLOT + (2 * i + g) * 2 + 1] = s;
    }
}

// Kernel 3: one wave per row. Lane l loads float2 {rowsum slot l, colsum slot l};
// exactly one is valid (l >= 2rb -> rowsum else colsum) -> select, reduce.
__global__ __launch_bounds__(256) void lse_kernel(const float* __restrict__ partial,
                                                  const float* __restrict__ pos,
                                                  float* __restrict__ blockSums) {
    const int lane = threadIdx.x & 63;
    const int wv   = threadIdx.x >> 6;
    const int r    = blockIdx.x * 4 + wv;
    const int rb   = r >> 8;
    float2 v = reinterpret_cast<const float2*>(partial + (size_t)r * NSLOT)[lane];
    float S = (lane >= 2 * rb) ? v.x : v.y;
    #pragma unroll
    for (int off = 32; off; off >>= 1) S += __shfl_xor(S, off);
    __shared__ float red[4];
    if (lane == 0) red[wv] = logf(S) - pos[r];
    __syncthreads();
    if (threadIdx.x == 0)
        blockSums[blockIdx.x] = red[0] + red[1] + red[2] + red[3];
}

// Kernel 4: reduce 2048 block sums -> loss
__global__ __launch_bounds__(256) void final_kernel(const float* __restrict__ bs,
                                                    float* __restrict__ out) {
    int t = threadIdx.x;
    float v = 0.0f;
    #pragma unroll
    for (int q = 0; q < LSE_BLOCKS / 256; ++q) v += bs[t + q * 256];
    #pragma unroll
    for (int off = 32; off; off >>= 1) v += __shfl_xor(v, off);
    __shared__ float red[4];
    if ((t & 63) == 0) red[t >> 6] = v;
    __syncthreads();
    if (t == 0) out[0] = (red[0] + red[1] + red[2] + red[3]) / (float)N_TOT;
}

extern "C" void kernel_launch(void* const* d_in, const int* in_sizes, int n_in,
                              void* d_out, int out_size, void* d_ws, size_t ws_size,
                              hipStream_t stream) {
    const float* zi = (const float*)d_in[0];
    const float* zj = (const float*)d_in[1];
    char* ws = (char*)d_ws;

    unsigned char* znP = (unsigned char*)ws;                         // 2 MB
    float* pos        = (float*)(znP + (size_t)N_TOT * DIM);         // 32 KB
    float* partial    = pos + N_TOT;                                 // 8192*128*4 = 4 MB
    float* blockSums  = partial + (size_t)N_TOT * NSLOT;             // 8 KB
    float* out        = (float*)d_out;

    norm_kernel<<<N_TOT / 4, 256, 0, stream>>>(zi, zj, znP);
    sim_kernel<<<NBLK, 128, 0, stream>>>(znP, partial, pos);
    lse_kernel<<<LSE_BLOCKS, 256, 0, stream>>>(partial, pos, blockSums);
    final_kernel<<<1, 256, 0, stream>>>(blockSums, out);
}

// Round 16
// 37.902 us; speedup vs baseline: 1.5322x; 1.5322x over previous
//
#include <hip/hip_runtime.h>
#include <hip/hip_bf16.h>
#include <hip/hip_fp8.h>

#define N_TOT 8192
#define DIM 256                              // k elements = bytes (fp8)
#define HALF_B 4096
#define NCHUNK 32                            // 256-row chunks
#define NPAIR (NCHUNK * (NCHUNK + 1) / 2)    // 528 upper-tri pairs
#define NBLK (NPAIR * 4)                     // 2112 quarter-blocks (g,h)
#define TILE_COLS 32
#define NTILES 4                             // 4 x 32 = 128 cols per block
#define NSLOT 128                            // per-row: [2s]=rowsum slot s, [2s+1]=colsum slot s
#define LSE_BLOCKS (N_TOT / 4)               // 2048
#define KEXP 2.8853900817779268f             // (1/T=2) * log2(e)
#define TILE_BYTES (TILE_COLS * DIM)         // 8192 B per staged tile

typedef __attribute__((ext_vector_type(4))) float facc;      // 4 f32 accum
typedef __attribute__((ext_vector_type(2))) long long lpair; // 16B = 2 fp8 ksteps

typedef __attribute__((address_space(1))) const unsigned int guint;
typedef __attribute__((address_space(3))) unsigned int luint;

static __device__ __forceinline__ void gload16(const void* g, void* l) {
    __builtin_amdgcn_global_load_lds((guint*)g, (luint*)l, 16, 0, 0);
}
static __device__ __forceinline__ unsigned char f2fp8(float x) {
    __hip_fp8_e4m3 h(x);
    return (unsigned char)h.__x;
}
static __device__ __forceinline__ float fast_exp2(float x) {
#if __has_builtin(__builtin_amdgcn_exp2f)
    return __builtin_amdgcn_exp2f(x);
#else
    return exp2f(x);
#endif
}
static __device__ __forceinline__ facc mfma8(long long a, long long b, facc c) {
    return __builtin_amdgcn_mfma_f32_16x16x32_fp8_fp8(a, b, c, 0, 0, 0);
}

// Kernel 1: row-normalize concat(z_i, z_j) -> fp8 znP, kq-major permuted rows
__global__ __launch_bounds__(256) void norm_kernel(const float* __restrict__ zi,
                                                   const float* __restrict__ zj,
                                                   unsigned char* __restrict__ znP) {
    int row  = blockIdx.x * 4 + (threadIdx.x >> 6);
    int lane = threadIdx.x & 63;
    const float* src = (row < HALF_B) ? (zi + (size_t)row * DIM)
                                      : (zj + (size_t)(row - HALF_B) * DIM);
    float4 v = reinterpret_cast<const float4*>(src)[lane];
    float ss = v.x * v.x + v.y * v.y + v.z * v.z + v.w * v.w;
    #pragma unroll
    for (int off = 32; off; off >>= 1) ss += __shfl_xor(ss, off);
    float inv = 1.0f / fmaxf(sqrtf(ss), 1e-8f);
    uchar4 o;
    o.x = f2fp8(v.x * inv);
    o.y = f2fp8(v.y * inv);
    o.z = f2fp8(v.z * inv);
    o.w = f2fp8(v.w * inv);
    int b = lane * 4;                 // natural byte offset
    int g = b >> 3;                   // granule: natural g = ks*4+kq
    int pb = ((((g & 3) << 3) | (g >> 2)) << 3) | (b & 7);   // permuted = kq*8+ks
    *reinterpret_cast<uchar4*>(znP + (size_t)row * DIM + pb) = o;
}

// Kernel 2: symmetric fused zn@zn^T (fp8 MFMA) + exp sums + pos extraction.
// Block = quarter (i,j,g,h): rows = chunk i half g (128), cols = chunk j half h (128).
// R12 math, new sync: ALL 4 tiles staged into 4 single-use LDS buffers in the
// prologue; per tile t only `s_waitcnt vmcnt(6-2t)` + raw s_barrier (no full
// drain until the last tile). pos values stashed in regs, stored after loop
// (keeps vmcnt counting pure: 8 A-loads oldest, 8 stage-loads newest).
__global__ __launch_bounds__(256, 4) void sim_kernel(const unsigned char* __restrict__ znP,
                                                     float* __restrict__ partial,
                                                     float* __restrict__ pos) {
    __shared__ __align__(16) unsigned char smem[4 * TILE_BYTES];   // 32KB, single-use
    __shared__ float colred[4][128];                               // 2KB
    const int lane = threadIdx.x & 63;
    const int wv   = threadIdx.x >> 6;
    const int lrow = lane & 15;         // A-row / B-col within 16
    const int kq   = lane >> 4;         // k-group 0..3

    // decode block -> (i, j, g, h)
    const int pairId = blockIdx.x >> 2;
    const int h      = blockIdx.x & 1;
    const int g      = (blockIdx.x >> 1) & 1;
    int i = 0, rem = pairId;
    while (rem >= NCHUNK - i) { rem -= NCHUNK - i; ++i; }
    const int j = i + rem;
    const int rowBase  = i * 256 + g * 128 + wv * 32;
    const int colStart = j * 256 + h * 128;

    // staging addresses: tile = 32 rows x 16 chunks(16B) = 512 chunks; 2/thread
    int srcOff[2];
    #pragma unroll
    for (int q = 0; q < 2; ++q) {
        int c  = (wv * 2 + q) * 64 + lane;   // chunk id 0..511
        int r  = c >> 4;                     // tile row 0..31
        int cc = c & 15;                     // chunk-in-row (k-pair slot)
        srcOff[q] = r * DIM + ((cc ^ (r & 15)) << 4);   // pre-swizzled source
    }
    const unsigned char* znPC = znP + (size_t)colStart * DIM;

    // ---- A fragments FIRST (oldest vmcnt slots 1..8) ----
    lpair a[2][4];
    #pragma unroll
    for (int t = 0; t < 2; ++t)
        #pragma unroll
        for (int s = 0; s < 4; ++s)
            a[t][s] = *reinterpret_cast<const lpair*>(
                znP + (size_t)(rowBase + t * 16 + lrow) * DIM + kq * 64 + s * 16);
    __builtin_amdgcn_sched_barrier(0);      // keep A-loads before stage-loads

    // ---- stage ALL 4 tiles (vmcnt slots 9..16, 2 per tile, program order) ----
#define STAGE(buf, ct) do {                                                   \
        const unsigned char* gsb = znPC + (size_t)(ct) * TILE_BYTES;          \
        _Pragma("unroll")                                                     \
        for (int q = 0; q < 2; ++q)                                           \
            gload16(gsb + srcOff[q],                                          \
                    smem + (buf) * TILE_BYTES + (wv * 2 + q) * 1024);         \
    } while (0)
    STAGE(0, 0);
    STAGE(1, 1);
    STAGE(2, 2);
    STAGE(3, 3);
#undef STAGE
    __builtin_amdgcn_sched_barrier(0);      // keep stages before the pins

    // pins force the compiler to wait only for A (vmcnt(8): stages in flight)
    #pragma unroll
    for (int t = 0; t < 2; ++t)
        #pragma unroll
        for (int s = 0; s < 4; ++s)
            asm volatile("" : "+v"(a[t][s]));

    float rowsum[2][4];
    #pragma unroll
    for (int t = 0; t < 2; ++t)
        #pragma unroll
        for (int jj = 0; jj < 4; ++jj) rowsum[t][jj] = 0.0f;
    float pst[2] = {0.0f, 0.0f};            // pos stashes (t=0,1)

    colred[wv][lane]      = 0.0f;           // per-wave private row
    colred[wv][lane + 64] = 0.0f;

    // ---- tile body (R12 math; pos -> stash instead of store) ----
#define TILE_BODY(T) do {                                                     \
        const unsigned char* tb = smem + (T) * TILE_BYTES;                    \
        _Pragma("unroll")                                                     \
        for (int cs = 0; cs < 2; ++cs) {                                      \
            const unsigned char* base = tb + (cs * 16 + lrow) * DIM;          \
            facc acc[2];                                                      \
            acc[0] = (facc){0.f, 0.f, 0.f, 0.f};                              \
            acc[1] = (facc){0.f, 0.f, 0.f, 0.f};                              \
            _Pragma("unroll")                                                 \
            for (int s = 0; s < 4; ++s) {                                     \
                lpair bv = *reinterpret_cast<const lpair*>(                   \
                    base + (((kq * 4 + s) ^ lrow) << 4));                     \
                _Pragma("unroll")                                             \
                for (int t = 0; t < 2; ++t) {                                 \
                    acc[t] = mfma8(a[t][s][0], bv[0], acc[t]);                \
                    acc[t] = mfma8(a[t][s][1], bv[1], acc[t]);                \
                }                                                             \
            }                                                                 \
            const int colBase = colStart + (T) * TILE_COLS + cs * 16;         \
            float csum = 0.0f;                                                \
            _Pragma("unroll")                                                 \
            for (int t = 0; t < 2; ++t) {                                     \
                const int tRowBase = rowBase + t * 16;                        \
                if (colBase == tRowBase) {                                    \
                    _Pragma("unroll")                                         \
                    for (int jj = 0; jj < 4; ++jj) {                          \
                        float e = fast_exp2(acc[t][jj] * KEXP);               \
                        if (lrow == kq * 4 + jj) e = 0.0f;                    \
                        rowsum[t][jj] += e;                                   \
                        csum += e;                                            \
                    }                                                         \
                } else if (colBase == tRowBase + HALF_B) {                    \
                    _Pragma("unroll")                                         \
                    for (int jj = 0; jj < 4; ++jj) {                          \
                        float e = fast_exp2(acc[t][jj] * KEXP);               \
                        rowsum[t][jj] += e;                                   \
                        csum += e;                                            \
                        if (lrow == kq * 4 + jj)                              \
                            pst[t] = acc[t][jj] * 2.0f;                       \
                    }                                                         \
                } else {                                                      \
                    _Pragma("unroll")                                         \
                    for (int jj = 0; jj < 4; ++jj) {                          \
                        float e = fast_exp2(acc[t][jj] * KEXP);               \
                        rowsum[t][jj] += e;                                   \
                        csum += e;                                            \
                    }                                                         \
                }                                                             \
            }                                                                 \
            csum += __shfl_xor(csum, 16);                                     \
            csum += __shfl_xor(csum, 32);                                     \
            if (kq == 0)                                                      \
                colred[wv][(T) * TILE_COLS + cs * 16 + lrow] += csum;         \
        }                                                                     \
    } while (0)

    // ---- counted-vmcnt pipeline: tile t ready at vmcnt(6-2t) ----
    asm volatile("s_waitcnt vmcnt(6)" ::: "memory");
    __builtin_amdgcn_s_barrier();
    __builtin_amdgcn_sched_barrier(0);
    TILE_BODY(0);
    asm volatile("s_waitcnt vmcnt(4)" ::: "memory");
    __builtin_amdgcn_s_barrier();
    __builtin_amdgcn_sched_barrier(0);
    TILE_BODY(1);
    asm volatile("s_waitcnt vmcnt(2)" ::: "memory");
    __builtin_amdgcn_s_barrier();
    __builtin_amdgcn_sched_barrier(0);
    TILE_BODY(2);
    asm volatile("s_waitcnt vmcnt(0)" ::: "memory");
    __builtin_amdgcn_s_barrier();
    __builtin_amdgcn_sched_barrier(0);
    TILE_BODY(3);
#undef TILE_BODY

    // pos stores (outside the counted region); block is pos-type iff j==i+16, g==h
    if (j == i + 16 && g == h) {
        int jj = lrow - kq * 4;
        if (jj >= 0 && jj < 4) {
            int r0 = rowBase + lrow;            // t = 0 row
            int r1 = rowBase + 16 + lrow;       // t = 1 row
            pos[r0]          = pst[0];
            pos[r0 + HALF_B] = pst[0];
            pos[r1]          = pst[1];
            pos[r1 + HALF_B] = pst[1];
        }
    }

    // rowsum: reduce across 16 lrow lanes -> partial[row][2*(2j+h)]
    const int offR = (j * 2 + h) * 2;
    #pragma unroll
    for (int t = 0; t < 2; ++t)
        #pragma unroll
        for (int jj = 0; jj < 4; ++jj) {
            float v = rowsum[t][jj];
            v += __shfl_xor(v, 1);
            v += __shfl_xor(v, 2);
            v += __shfl_xor(v, 4);
            v += __shfl_xor(v, 8);
            if (lrow == 0)
                partial[(size_t)(rowBase + t * 16 + kq * 4 + jj) * NSLOT + offR] = v;
        }

    // colsum: cross-wave reduce -> partial[col][2*(2i+g)+1]
    __syncthreads();
    if (i != j && threadIdx.x < 128) {
        int c = threadIdx.x;
        float s = colred[0][c] + colred[1][c] + colred[2][c] + colred[3][c];
        partial[(size_t)(colStart + c) * NSLOT + (2 * i + g) * 2 + 1] = s;
    }
}

// Kernel 3: one wave per row. Lane l loads float2 {rowsum slot l, colsum slot l};
// exactly one is valid (l >= 2rb -> rowsum else colsum) -> select, reduce.
__global__ __launch_bounds__(256) void lse_kernel(const float* __restrict__ partial,
                                                  const float* __restrict__ pos,
                                                  float* __restrict__ blockSums) {
    const int lane = threadIdx.x & 63;
    const int wv   = threadIdx.x >> 6;
    const int r    = blockIdx.x * 4 + wv;
    const int rb   = r >> 8;
    float2 v = reinterpret_cast<const float2*>(partial + (size_t)r * NSLOT)[lane];
    float S = (lane >= 2 * rb) ? v.x : v.y;
    #pragma unroll
    for (int off = 32; off; off >>= 1) S += __shfl_xor(S, off);
    __shared__ float red[4];
    if (lane == 0) red[wv] = logf(S) - pos[r];
    __syncthreads();
    if (threadIdx.x == 0)
        blockSums[blockIdx.x] = red[0] + red[1] + red[2] + red[3];
}

// Kernel 4: reduce 2048 block sums -> loss
__global__ __launch_bounds__(256) void final_kernel(const float* __restrict__ bs,
                                                    float* __restrict__ out) {
    int t = threadIdx.x;
    float v = 0.0f;
    #pragma unroll
    for (int q = 0; q < LSE_BLOCKS / 256; ++q) v += bs[t + q * 256];
    #pragma unroll
    for (int off = 32; off; off >>= 1) v += __shfl_xor(v, off);
    __shared__ float red[4];
    if ((t & 63) == 0) red[t >> 6] = v;
    __syncthreads();
    if (t == 0) out[0] = (red[0] + red[1] + red[2] + red[3]) / (float)N_TOT;
}

extern "C" void kernel_launch(void* const* d_in, const int* in_sizes, int n_in,
                              void* d_out, int out_size, void* d_ws, size_t ws_size,
                              hipStream_t stream) {
    const float* zi = (const float*)d_in[0];
    const float* zj = (const float*)d_in[1];
    char* ws = (char*)d_ws;

    unsigned char* znP = (unsigned char*)ws;                         // 2 MB
    float* pos        = (float*)(znP + (size_t)N_TOT * DIM);         // 32 KB
    float* partial    = pos + N_TOT;                                 // 8192*128*4 = 4 MB
    float* blockSums  = partial + (size_t)N_TOT * NSLOT;             // 8 KB
    float* out        = (float*)d_out;

    norm_kernel<<<N_TOT / 4, 256, 0, stream>>>(zi, zj, znP);
    sim_kernel<<<NBLK, 256, 0, stream>>>(znP, partial, pos);
    lse_kernel<<<LSE_BLOCKS, 256, 0, stream>>>(partial, pos, blockSums);
    final_kernel<<<1, 256, 0, stream>>>(blockSums, out);
}

// Round 17
// 37.353 us; speedup vs baseline: 1.5548x; 1.0147x over previous
//
#include <hip/hip_runtime.h>
#include <hip/hip_bf16.h>
#include <hip/hip_fp8.h>

#define N_TOT 8192
#define DIM 256                              // k elements = bytes (fp8)
#define HALF_B 4096
#define NCHUNK 32                            // 256-row chunks
#define NPAIR (NCHUNK * (NCHUNK + 1) / 2)    // 528 upper-tri pairs
#define NBLK (NPAIR * 4)                     // 2112 quarter-blocks (g,h)
#define TILE_COLS 32
#define NTILES 4                             // 4 x 32 = 128 cols per block
#define NSLOT 128                            // per-row: [2s]=rowsum slot s, [2s+1]=colsum slot s
#define LSE_BLOCKS (N_TOT / 4)               // 2048
#define KEXP 2.8853900817779268f             // (1/T=2) * log2(e)
#define TILE_BYTES (TILE_COLS * DIM)         // 8192 B per staged tile

typedef __attribute__((ext_vector_type(4))) float facc;      // 4 f32 accum
typedef __attribute__((ext_vector_type(2))) long long lpair; // 16B = 2 fp8 ksteps

typedef __attribute__((address_space(1))) const unsigned int guint;
typedef __attribute__((address_space(3))) unsigned int luint;

static __device__ __forceinline__ void gload16(const void* g, void* l) {
    __builtin_amdgcn_global_load_lds((guint*)g, (luint*)l, 16, 0, 0);
}
static __device__ __forceinline__ unsigned char f2fp8(float x) {
    __hip_fp8_e4m3 h(x);
    return (unsigned char)h.__x;
}
static __device__ __forceinline__ float fast_exp2(float x) {
    float r;
    asm("v_exp_f32 %0, %1" : "=v"(r) : "v"(x));   // single TRANS op, D = 2^S0
    return r;
}
static __device__ __forceinline__ facc mfma8(long long a, long long b, facc c) {
    return __builtin_amdgcn_mfma_f32_16x16x32_fp8_fp8(a, b, c, 0, 0, 0);
}

// Kernel 1: row-normalize concat(z_i, z_j) -> fp8 znP, kq-major permuted rows
__global__ __launch_bounds__(256) void norm_kernel(const float* __restrict__ zi,
                                                   const float* __restrict__ zj,
                                                   unsigned char* __restrict__ znP) {
    int row  = blockIdx.x * 4 + (threadIdx.x >> 6);
    int lane = threadIdx.x & 63;
    const float* src = (row < HALF_B) ? (zi + (size_t)row * DIM)
                                      : (zj + (size_t)(row - HALF_B) * DIM);
    float4 v = reinterpret_cast<const float4*>(src)[lane];
    float ss = v.x * v.x + v.y * v.y + v.z * v.z + v.w * v.w;
    #pragma unroll
    for (int off = 32; off; off >>= 1) ss += __shfl_xor(ss, off);
    float inv = 1.0f / fmaxf(sqrtf(ss), 1e-8f);
    uchar4 o;
    o.x = f2fp8(v.x * inv);
    o.y = f2fp8(v.y * inv);
    o.z = f2fp8(v.z * inv);
    o.w = f2fp8(v.w * inv);
    int b = lane * 4;                 // natural byte offset
    int g = b >> 3;                   // granule: natural g = ks*4+kq
    int pb = ((((g & 3) << 3) | (g >> 2)) << 3) | (b & 7);   // permuted = kq*8+ks
    *reinterpret_cast<uchar4*>(znP + (size_t)row * DIM + pb) = o;
}

// Kernel 2: symmetric fused zn@zn^T (fp8 MFMA) + exp sums + pos extraction.
// R16 skeleton (counted-vmcnt, 4 single-use LDS tile bufs). Epilogue thinned:
// colsum via write-once colred[8][128] (one shfl_xor(32), pure ds_write, no
// RMW/zeroing); exp = 1x v_exp_f32.
__global__ __launch_bounds__(256, 4) void sim_kernel(const unsigned char* __restrict__ znP,
                                                     float* __restrict__ partial,
                                                     float* __restrict__ pos) {
    __shared__ __align__(16) unsigned char smem[4 * TILE_BYTES];   // 32KB, single-use
    __shared__ float colred[8][128];                               // 4KB, write-once
    const int lane = threadIdx.x & 63;
    const int wv   = threadIdx.x >> 6;
    const int lrow = lane & 15;         // A-row / B-col within 16
    const int kq   = lane >> 4;         // k-group 0..3

    // decode block -> (i, j, g, h)
    const int pairId = blockIdx.x >> 2;
    const int h      = blockIdx.x & 1;
    const int g      = (blockIdx.x >> 1) & 1;
    int i = 0, rem = pairId;
    while (rem >= NCHUNK - i) { rem -= NCHUNK - i; ++i; }
    const int j = i + rem;
    const int rowBase  = i * 256 + g * 128 + wv * 32;
    const int colStart = j * 256 + h * 128;

    // staging addresses: tile = 32 rows x 16 chunks(16B) = 512 chunks; 2/thread
    int srcOff[2];
    #pragma unroll
    for (int q = 0; q < 2; ++q) {
        int c  = (wv * 2 + q) * 64 + lane;   // chunk id 0..511
        int r  = c >> 4;                     // tile row 0..31
        int cc = c & 15;                     // chunk-in-row (k-pair slot)
        srcOff[q] = r * DIM + ((cc ^ (r & 15)) << 4);   // pre-swizzled source
    }
    const unsigned char* znPC = znP + (size_t)colStart * DIM;

    // ---- A fragments FIRST (oldest vmcnt slots) ----
    lpair a[2][4];
    #pragma unroll
    for (int t = 0; t < 2; ++t)
        #pragma unroll
        for (int s = 0; s < 4; ++s)
            a[t][s] = *reinterpret_cast<const lpair*>(
                znP + (size_t)(rowBase + t * 16 + lrow) * DIM + kq * 64 + s * 16);
    __builtin_amdgcn_sched_barrier(0);      // keep A-loads before stage-loads

    // ---- stage ALL 4 tiles (2 loads per tile, program order) ----
#define STAGE(buf, ct) do {                                                   \
        const unsigned char* gsb = znPC + (size_t)(ct) * TILE_BYTES;          \
        _Pragma("unroll")                                                     \
        for (int q = 0; q < 2; ++q)                                           \
            gload16(gsb + srcOff[q],                                          \
                    smem + (buf) * TILE_BYTES + (wv * 2 + q) * 1024);         \
    } while (0)
    STAGE(0, 0);
    STAGE(1, 1);
    STAGE(2, 2);
    STAGE(3, 3);
#undef STAGE
    __builtin_amdgcn_sched_barrier(0);      // keep stages before the pins

    // pins: compiler waits only for A here (stages stay in flight)
    #pragma unroll
    for (int t = 0; t < 2; ++t)
        #pragma unroll
        for (int s = 0; s < 4; ++s)
            asm volatile("" : "+v"(a[t][s]));

    float rowsum[2][4];
    #pragma unroll
    for (int t = 0; t < 2; ++t)
        #pragma unroll
        for (int jj = 0; jj < 4; ++jj) rowsum[t][jj] = 0.0f;
    float pst[2] = {0.0f, 0.0f};            // pos stashes (t=0,1)

    // ---- tile body (colsum: 1 shfl_xor(32) + write-once ds_write) ----
#define TILE_BODY(T) do {                                                     \
        const unsigned char* tb = smem + (T) * TILE_BYTES;                    \
        _Pragma("unroll")                                                     \
        for (int cs = 0; cs < 2; ++cs) {                                      \
            const unsigned char* base = tb + (cs * 16 + lrow) * DIM;          \
            facc acc[2];                                                      \
            acc[0] = (facc){0.f, 0.f, 0.f, 0.f};                              \
            acc[1] = (facc){0.f, 0.f, 0.f, 0.f};                              \
            _Pragma("unroll")                                                 \
            for (int s = 0; s < 4; ++s) {                                     \
                lpair bv = *reinterpret_cast<const lpair*>(                   \
                    base + (((kq * 4 + s) ^ lrow) << 4));                     \
                _Pragma("unroll")                                             \
                for (int t = 0; t < 2; ++t) {                                 \
                    acc[t] = mfma8(a[t][s][0], bv[0], acc[t]);                \
                    acc[t] = mfma8(a[t][s][1], bv[1], acc[t]);                \
                }                                                             \
            }                                                                 \
            const int colBase = colStart + (T) * TILE_COLS + cs * 16;         \
            float csum = 0.0f;                                                \
            _Pragma("unroll")                                                 \
            for (int t = 0; t < 2; ++t) {                                     \
                const int tRowBase = rowBase + t * 16;                        \
                if (colBase == tRowBase) {                                    \
                    _Pragma("unroll")                                         \
                    for (int jj = 0; jj < 4; ++jj) {                          \
                        float e = fast_exp2(acc[t][jj] * KEXP);               \
                        if (lrow == kq * 4 + jj) e = 0.0f;                    \
                        rowsum[t][jj] += e;                                   \
                        csum += e;                                            \
                    }                                                         \
                } else if (colBase == tRowBase + HALF_B) {                    \
                    _Pragma("unroll")                                         \
                    for (int jj = 0; jj < 4; ++jj) {                          \
                        float e = fast_exp2(acc[t][jj] * KEXP);               \
                        rowsum[t][jj] += e;                                   \
                        csum += e;                                            \
                        if (lrow == kq * 4 + jj)                              \
                            pst[t] = acc[t][jj] * 2.0f;                       \
                    }                                                         \
                } else {                                                      \
                    _Pragma("unroll")                                         \
                    for (int jj = 0; jj < 4; ++jj) {                          \
                        float e = fast_exp2(acc[t][jj] * KEXP);               \
                        rowsum[t][jj] += e;                                   \
                        csum += e;                                            \
                    }                                                         \
                }                                                             \
            }                                                                 \
            csum += __shfl_xor(csum, 32);          /* fold kq^2 */            \
            if (kq < 2)                            /* write-once, no RMW */   \
                colred[wv * 2 + kq][(T) * TILE_COLS + cs * 16 + lrow] = csum; \
        }                                                                     \
    } while (0)

    // ---- counted-vmcnt pipeline: tile t ready at vmcnt(6-2t) ----
    asm volatile("s_waitcnt vmcnt(6)" ::: "memory");
    __builtin_amdgcn_s_barrier();
    __builtin_amdgcn_sched_barrier(0);
    TILE_BODY(0);
    asm volatile("s_waitcnt vmcnt(4)" ::: "memory");
    __builtin_amdgcn_s_barrier();
    __builtin_amdgcn_sched_barrier(0);
    TILE_BODY(1);
    asm volatile("s_waitcnt vmcnt(2)" ::: "memory");
    __builtin_amdgcn_s_barrier();
    __builtin_amdgcn_sched_barrier(0);
    TILE_BODY(2);
    asm volatile("s_waitcnt vmcnt(0)" ::: "memory");
    __builtin_amdgcn_s_barrier();
    __builtin_amdgcn_sched_barrier(0);
    TILE_BODY(3);
#undef TILE_BODY

    // pos stores (outside the counted region); pos-type iff j==i+16, g==h
    if (j == i + 16 && g == h) {
        int jj = lrow - kq * 4;
        if (jj >= 0 && jj < 4) {
            int r0 = rowBase + lrow;            // t = 0 row
            int r1 = rowBase + 16 + lrow;       // t = 1 row
            pos[r0]          = pst[0];
            pos[r0 + HALF_B] = pst[0];
            pos[r1]          = pst[1];
            pos[r1 + HALF_B] = pst[1];
        }
    }

    // rowsum: reduce across 16 lrow lanes -> partial[row][2*(2j+h)]
    const int offR = (j * 2 + h) * 2;
    #pragma unroll
    for (int t = 0; t < 2; ++t)
        #pragma unroll
        for (int jj = 0; jj < 4; ++jj) {
            float v = rowsum[t][jj];
            v += __shfl_xor(v, 1);
            v += __shfl_xor(v, 2);
            v += __shfl_xor(v, 4);
            v += __shfl_xor(v, 8);
            if (lrow == 0)
                partial[(size_t)(rowBase + t * 16 + kq * 4 + jj) * NSLOT + offR] = v;
        }

    // colsum: cross-wave reduce of the 8 write-once rows
    __syncthreads();
    if (i != j && threadIdx.x < 128) {
        int c = threadIdx.x;
        float s = 0.0f;
        #pragma unroll
        for (int r8 = 0; r8 < 8; ++r8) s += colred[r8][c];
        partial[(size_t)(colStart + c) * NSLOT + (2 * i + g) * 2 + 1] = s;
    }
}

// Kernel 3: one wave per row. Lane l loads float2 {rowsum slot l, colsum slot l};
// exactly one is valid (l >= 2rb -> rowsum else colsum) -> select, reduce.
__global__ __launch_bounds__(256) void lse_kernel(const float* __restrict__ partial,
                                                  const float* __restrict__ pos,
                                                  float* __restrict__ blockSums) {
    const int lane = threadIdx.x & 63;
    const int wv   = threadIdx.x >> 6;
    const int r    = blockIdx.x * 4 + wv;
    const int rb   = r >> 8;
    float2 v = reinterpret_cast<const float2*>(partial + (size_t)r * NSLOT)[lane];
    float S = (lane >= 2 * rb) ? v.x : v.y;
    #pragma unroll
    for (int off = 32; off; off >>= 1) S += __shfl_xor(S, off);
    __shared__ float red[4];
    if (lane == 0) red[wv] = logf(S) - pos[r];
    __syncthreads();
    if (threadIdx.x == 0)
        blockSums[blockIdx.x] = red[0] + red[1] + red[2] + red[3];
}

// Kernel 4: reduce 2048 block sums -> loss
__global__ __launch_bounds__(256) void final_kernel(const float* __restrict__ bs,
                                                    float* __restrict__ out) {
    int t = threadIdx.x;
    float v = 0.0f;
    #pragma unroll
    for (int q = 0; q < LSE_BLOCKS / 256; ++q) v += bs[t + q * 256];
    #pragma unroll
    for (int off = 32; off; off >>= 1) v += __shfl_xor(v, off);
    __shared__ float red[4];
    if ((t & 63) == 0) red[t >> 6] = v;
    __syncthreads();
    if (t == 0) out[0] = (red[0] + red[1] + red[2] + red[3]) / (float)N_TOT;
}

extern "C" void kernel_launch(void* const* d_in, const int* in_sizes, int n_in,
                              void* d_out, int out_size, void* d_ws, size_t ws_size,
                              hipStream_t stream) {
    const float* zi = (const float*)d_in[0];
    const float* zj = (const float*)d_in[1];
    char* ws = (char*)d_ws;

    unsigned char* znP = (unsigned char*)ws;                         // 2 MB
    float* pos        = (float*)(znP + (size_t)N_TOT * DIM);         // 32 KB
    float* partial    = pos + N_TOT;                                 // 8192*128*4 = 4 MB
    float* blockSums  = partial + (size_t)N_TOT * NSLOT;             // 8 KB
    float* out        = (float*)d_out;

    norm_kernel<<<N_TOT / 4, 256, 0, stream>>>(zi, zj, znP);
    sim_kernel<<<NBLK, 256, 0, stream>>>(znP, partial, pos);
    lse_kernel<<<LSE_BLOCKS, 256, 0, stream>>>(partial, pos, blockSums);
    final_kernel<<<1, 256, 0, stream>>>(blockSums, out);
}